// Round 2
// baseline (960.904 us; speedup 1.0000x reference)
//
#include <hip/hip_runtime.h>

#define BB 32
#define NN 4096
#define EE 65536
#define DS 8
#define ES 4
#define ENC 8
#define HH 16
#define OUTC 4
#define NI (NN * DS)
#define ROW (NN * OUTC - OUTC + 1)   // 16381 per-batch output row length
#define CSPLIT 16                    // critic K-dim split
#define CCHUNK (NI / CSPLIT)         // 2048

// ---------------- Kernel 1: node encoder x = relu(obs@W1+b1)@W2+b2 ; zero agg & hcrit ----------------
__global__ __launch_bounds__(256) void k_node_enc(
    const float* __restrict__ obs,
    const float* __restrict__ Wne1, const float* __restrict__ bne1,
    const float* __restrict__ Wne2, const float* __restrict__ bne2,
    float* __restrict__ x, float* __restrict__ agg, float* __restrict__ hcrit) {
  __shared__ float sW1[DS * HH], sb1[HH], sW2[HH * ENC], sb2[ENC];
  int t = threadIdx.x;
  if (t < DS * HH) sW1[t] = Wne1[t];
  if (t < HH)      sb1[t] = bne1[t];
  if (t < HH * ENC) sW2[t] = Wne2[t];
  if (t < ENC)     sb2[t] = bne2[t];
  if (blockIdx.x == 0) {             // zero critic partials (BB*HH = 512 floats)
    hcrit[t] = 0.f;
    hcrit[t + 256] = 0.f;
  }
  __syncthreads();
  int gid = blockIdx.x * 256 + t;    // node id in [0, B*N)
  if (gid >= BB * NN) return;

  const float4* op = (const float4*)(obs + (size_t)gid * DS);
  float4 o0 = op[0], o1 = op[1];
  float o[DS] = {o0.x, o0.y, o0.z, o0.w, o1.x, o1.y, o1.z, o1.w};

  float hb[HH];
#pragma unroll
  for (int j = 0; j < HH; ++j) {
    float a = sb1[j];
#pragma unroll
    for (int i = 0; i < DS; ++i) a += o[i] * sW1[i * HH + j];
    hb[j] = fmaxf(a, 0.f);
  }
  float e[ENC];
#pragma unroll
  for (int c = 0; c < ENC; ++c) {
    float a = sb2[c];
#pragma unroll
    for (int j = 0; j < HH; ++j) a += hb[j] * sW2[j * ENC + c];
    e[c] = a;
  }
  float4* xp = (float4*)(x + (size_t)gid * ENC);
  xp[0] = make_float4(e[0], e[1], e[2], e[3]);
  xp[1] = make_float4(e[4], e[5], e[6], e[7]);
  float4* ap = (float4*)(agg + (size_t)gid * ENC);
  ap[0] = make_float4(0.f, 0.f, 0.f, 0.f);
  ap[1] = make_float4(0.f, 0.f, 0.f, 0.f);
}

// ---------------- Kernel 2: per-edge encode + gather + relu + atomic scatter ----------------
__global__ __launch_bounds__(256) void k_edge(
    const float* __restrict__ eattr,
    const int* __restrict__ eidx,           // int32 per harness contract
    const float* __restrict__ Wee, const float* __restrict__ bee,
    const float* __restrict__ x, float* __restrict__ agg) {
  __shared__ float sW[ES * ENC], sb[ENC];
  int t = threadIdx.x;
  if (t < ES * ENC) sW[t] = Wee[t];
  if (t < ENC)      sb[t] = bee[t];
  __syncthreads();
  int gid = blockIdx.x * 256 + t;          // b*E + e, < 2^21
  if (gid >= BB * EE) return;
  int b = gid >> 16;                       // E = 65536
  int e = gid & (EE - 1);

  float4 at = ((const float4*)eattr)[gid]; // (b*E+e)*ES floats
  float av[ES] = {at.x, at.y, at.z, at.w};

  const int* ib = eidx + (size_t)b * 2 * EE;
  int src = ib[e];
  int dst = ib[EE + e];

  const float4* xr = (const float4*)(x + ((size_t)b * NN + src) * ENC);
  float4 x0 = xr[0], x1 = xr[1];
  float xv[ENC] = {x0.x, x0.y, x0.z, x0.w, x1.x, x1.y, x1.z, x1.w};

  float* ar = agg + ((size_t)b * NN + dst) * ENC;
#pragma unroll
  for (int c = 0; c < ENC; ++c) {
    float ea = sb[c];
#pragma unroll
    for (int s = 0; s < ES; ++s) ea += av[s] * sW[s * ENC + c];
    float m = fmaxf(xv[c] + ea, 0.f);
    atomicAdd(ar + c, m);
  }
}

// ---------------- Kernel 3: actor head, shifted output write ----------------
__global__ __launch_bounds__(256) void k_actor(
    const float* __restrict__ x, const float* __restrict__ agg,
    const float* __restrict__ Wa1, const float* __restrict__ ba1,
    const float* __restrict__ Wa2, const float* __restrict__ ba2,
    float* __restrict__ out) {
  __shared__ float sW1[ENC * HH], sb1[HH], sW2[HH * OUTC], sb2[OUTC];
  int t = threadIdx.x;
  if (t < ENC * HH)  sW1[t] = Wa1[t];
  if (t < HH)        sb1[t] = ba1[t];
  if (t < HH * OUTC) sW2[t] = Wa2[t];
  if (t < OUTC)      sb2[t] = ba2[t];
  __syncthreads();
  int gid = blockIdx.x * 256 + t;
  if (gid >= BB * NN) return;
  int b = gid >> 12;                       // N = 4096
  int n = gid & (NN - 1);

  const float4* xp = (const float4*)(x + (size_t)gid * ENC);
  const float4* ap = (const float4*)(agg + (size_t)gid * ENC);
  float4 xa = xp[0], xbv = xp[1], aa = ap[0], ab = ap[1];
  float v[ENC] = {xa.x + aa.x, xa.y + aa.y, xa.z + aa.z, xa.w + aa.w,
                  xbv.x + ab.x, xbv.y + ab.y, xbv.z + ab.z, xbv.w + ab.w};

  float hb[HH];
#pragma unroll
  for (int j = 0; j < HH; ++j) {
    float a = sb1[j];
#pragma unroll
    for (int i = 0; i < ENC; ++i) a += v[i] * sW1[i * HH + j];
    hb[j] = fmaxf(a, 0.f);
  }
  float o[OUTC];
#pragma unroll
  for (int c = 0; c < OUTC; ++c) {
    float a = sb2[c];
#pragma unroll
    for (int j = 0; j < HH; ++j) a += hb[j] * sW2[j * OUTC + c];
    o[c] = a;
  }
  if (n > 0) {
    // out[b, (n*OUT + c) - OUT] ; row length ROW (odd -> no float4 alignment)
    float* op = out + (size_t)b * ROW + (size_t)(n - 1) * OUTC;
    op[0] = o[0]; op[1] = o[1]; op[2] = o[2]; op[3] = o[3];
  }
}

// ---------------- Kernel 4: critic GEMV partials, grid = B*CSPLIT ----------------
__global__ __launch_bounds__(256) void k_critic_part(
    const float* __restrict__ obsf,
    const float* __restrict__ Wc1,
    float* __restrict__ hcrit) {
  int b = blockIdx.x / CSPLIT;
  int s = blockIdx.x % CSPLIT;
  int t = threadIdx.x;
  float acc[HH];
#pragma unroll
  for (int j = 0; j < HH; ++j) acc[j] = 0.f;

  const float* ob = obsf + (size_t)b * NI;
  int i0 = s * CCHUNK;
  for (int i = i0 + t; i < i0 + CCHUNK; i += 256) {
    float v = ob[i];
    const float4* wr = (const float4*)(Wc1 + (size_t)i * HH);
    float4 w0 = wr[0], w1 = wr[1], w2 = wr[2], w3 = wr[3];
    acc[0]  += v * w0.x; acc[1]  += v * w0.y; acc[2]  += v * w0.z; acc[3]  += v * w0.w;
    acc[4]  += v * w1.x; acc[5]  += v * w1.y; acc[6]  += v * w1.z; acc[7]  += v * w1.w;
    acc[8]  += v * w2.x; acc[9]  += v * w2.y; acc[10] += v * w2.z; acc[11] += v * w2.w;
    acc[12] += v * w3.x; acc[13] += v * w3.y; acc[14] += v * w3.z; acc[15] += v * w3.w;
  }

  __shared__ float red[4][HH];
  int wid = t >> 6, lane = t & 63;
#pragma unroll
  for (int j = 0; j < HH; ++j) {
    float a = acc[j];
#pragma unroll
    for (int off = 32; off >= 1; off >>= 1) a += __shfl_down(a, off, 64);
    if (lane == 0) red[wid][j] = a;
  }
  __syncthreads();
  if (t < HH) {
    float a = red[0][t] + red[1][t] + red[2][t] + red[3][t];
    atomicAdd(hcrit + b * HH + t, a);
  }
}

// ---------------- Kernel 5: critic finish ----------------
__global__ __launch_bounds__(64) void k_critic_fin(
    const float* __restrict__ hcrit,
    const float* __restrict__ bc1,
    const float* __restrict__ Wc2, const float* __restrict__ bc2,
    float* __restrict__ out) {
  int b = threadIdx.x;
  if (b >= BB) return;
  float val = bc2[0];
#pragma unroll
  for (int j = 0; j < HH; ++j) {
    float h = hcrit[b * HH + j] + bc1[j];
    val += fmaxf(h, 0.f) * Wc2[j];
  }
  out[(size_t)b * ROW + (ROW - 1)] = val;
}

extern "C" void kernel_launch(void* const* d_in, const int* in_sizes, int n_in,
                              void* d_out, int out_size, void* d_ws, size_t ws_size,
                              hipStream_t stream) {
  const float* agent_obs  = (const float*)d_in[0];
  const float* edge_attr  = (const float*)d_in[1];
  const float* obs_flat   = (const float*)d_in[2];
  const int*   edge_index = (const int*)d_in[3];
  const float* W_ne1 = (const float*)d_in[4];
  const float* b_ne1 = (const float*)d_in[5];
  const float* W_ne2 = (const float*)d_in[6];
  const float* b_ne2 = (const float*)d_in[7];
  const float* W_ee  = (const float*)d_in[8];
  const float* b_ee  = (const float*)d_in[9];
  const float* W_a1  = (const float*)d_in[10];
  const float* b_a1  = (const float*)d_in[11];
  const float* W_a2  = (const float*)d_in[12];
  const float* b_a2  = (const float*)d_in[13];
  const float* W_c1  = (const float*)d_in[14];
  const float* b_c1  = (const float*)d_in[15];
  const float* W_c2  = (const float*)d_in[16];
  const float* b_c2  = (const float*)d_in[17];
  float* out = (float*)d_out;

  float* x_buf   = (float*)d_ws;                         // B*N*ENC f32 = 4 MB
  float* agg_buf = x_buf + (size_t)BB * NN * ENC;        // B*N*ENC f32 = 4 MB
  float* hcrit   = agg_buf + (size_t)BB * NN * ENC;      // B*HH f32 = 2 KB

  dim3 blk(256);
  k_node_enc<<<dim3((BB * NN) / 256), blk, 0, stream>>>(
      agent_obs, W_ne1, b_ne1, W_ne2, b_ne2, x_buf, agg_buf, hcrit);
  k_edge<<<dim3((BB * EE) / 256), blk, 0, stream>>>(
      edge_attr, edge_index, W_ee, b_ee, x_buf, agg_buf);
  k_actor<<<dim3((BB * NN) / 256), blk, 0, stream>>>(
      x_buf, agg_buf, W_a1, b_a1, W_a2, b_a2, out);
  k_critic_part<<<dim3(BB * CSPLIT), blk, 0, stream>>>(
      obs_flat, W_c1, hcrit);
  k_critic_fin<<<dim3(1), dim3(64), 0, stream>>>(
      hcrit, b_c1, W_c2, b_c2, out);
}

// Round 3
// 222.920 us; speedup vs baseline: 4.3105x; 4.3105x over previous
//
#include <hip/hip_runtime.h>

#define BB 32
#define NN 4096
#define EE 65536
#define DS 8
#define ES 4
#define ENC 8
#define HH 16
#define OUTC 4
#define NI (NN * DS)
#define ROW (NN * OUTC - OUTC + 1)   // 16381 per-batch output row length
#define CSPLIT 16                    // critic K-dim split
#define CCHUNK (NI / CSPLIT)         // 2048
#define NHALF 2048                   // node-half per edge block
#define ESPLIT 4                     // edge-chunk splits per (b, half)
#define EPBE (EE / ESPLIT)           // 16384 edges per block

// ---------------- Kernel 1: node encoder x = relu(obs@W1+b1)@W2+b2 ; zero hcrit ----------------
__global__ __launch_bounds__(256) void k_node_enc(
    const float* __restrict__ obs,
    const float* __restrict__ Wne1, const float* __restrict__ bne1,
    const float* __restrict__ Wne2, const float* __restrict__ bne2,
    float* __restrict__ x, float* __restrict__ hcrit) {
  __shared__ float sW1[DS * HH], sb1[HH], sW2[HH * ENC], sb2[ENC];
  int t = threadIdx.x;
  if (t < DS * HH) sW1[t] = Wne1[t];
  if (t < HH)      sb1[t] = bne1[t];
  if (t < HH * ENC) sW2[t] = Wne2[t];
  if (t < ENC)     sb2[t] = bne2[t];
  if (blockIdx.x == 0) {             // zero critic partials (BB*HH = 512 floats)
    hcrit[t] = 0.f;
    hcrit[t + 256] = 0.f;
  }
  __syncthreads();
  int gid = blockIdx.x * 256 + t;    // node id in [0, B*N)
  if (gid >= BB * NN) return;

  const float4* op = (const float4*)(obs + (size_t)gid * DS);
  float4 o0 = op[0], o1 = op[1];
  float o[DS] = {o0.x, o0.y, o0.z, o0.w, o1.x, o1.y, o1.z, o1.w};

  float hb[HH];
#pragma unroll
  for (int j = 0; j < HH; ++j) {
    float a = sb1[j];
#pragma unroll
    for (int i = 0; i < DS; ++i) a += o[i] * sW1[i * HH + j];
    hb[j] = fmaxf(a, 0.f);
  }
  float e[ENC];
#pragma unroll
  for (int c = 0; c < ENC; ++c) {
    float a = sb2[c];
#pragma unroll
    for (int j = 0; j < HH; ++j) a += hb[j] * sW2[j * ENC + c];
    e[c] = a;
  }
  float4* xp = (float4*)(x + (size_t)gid * ENC);
  xp[0] = make_float4(e[0], e[1], e[2], e[3]);
  xp[1] = make_float4(e[4], e[5], e[6], e[7]);
}

// ---------------- Kernel 2: edge encode + gather + relu + LDS-privatized scatter ----------------
// grid = BB * 2 * ESPLIT = 256 blocks, 1024 threads.
// Logical id L = b*8 + s*2 + h  (h = node half, s = edge chunk).
// Physical->logical swizzle groups all 8 blocks of a batch-quad on one XCD so
// the h=0/h=1 pair re-reading the same attr/idx chunk hits L2.
__global__ __launch_bounds__(1024) void k_edge_lds(
    const float* __restrict__ eattr,
    const int* __restrict__ eidx,
    const float* __restrict__ Wee, const float* __restrict__ bee,
    const float* __restrict__ x,
    float* __restrict__ partial) {          // [BB*8][NHALF][ENC]
  __shared__ float sagg[ENC * NHALF];       // 64 KB, [ch][node'] -> bank = node'%32
  int p = blockIdx.x;
  int L = (p & 7) * 32 + (p >> 3);
  int b = L >> 3, s = (L >> 1) & 3, h = L & 1;
  int t = threadIdx.x;
  int base = h * NHALF;

  float w[ES * ENC], bb[ENC];
#pragma unroll
  for (int i = 0; i < ES * ENC; ++i) w[i] = Wee[i];
#pragma unroll
  for (int c = 0; c < ENC; ++c) bb[c] = bee[c];

  for (int i = t; i < ENC * NHALF; i += 1024) sagg[i] = 0.f;
  __syncthreads();

  const int*   ibs = eidx + (size_t)b * 2 * EE + (size_t)s * EPBE;
  const int*   ibd = ibs + EE;
  const float* ab  = eattr + ((size_t)b * EE + (size_t)s * EPBE) * ES;
  const float* xb  = x + (size_t)b * NN * ENC;

  for (int k = t; k < EPBE; k += 1024) {
    int dst = ibd[k];
    unsigned off = (unsigned)(dst - base);
    if (off < (unsigned)NHALF) {
      int src = ibs[k];
      float4 at = ((const float4*)ab)[k];
      const float4* xr = (const float4*)(xb + (size_t)src * ENC);
      float4 x0 = xr[0], x1 = xr[1];
      float xv[ENC] = {x0.x, x0.y, x0.z, x0.w, x1.x, x1.y, x1.z, x1.w};
      float av[ES] = {at.x, at.y, at.z, at.w};
#pragma unroll
      for (int c = 0; c < ENC; ++c) {
        float ea = bb[c];
#pragma unroll
        for (int i2 = 0; i2 < ES; ++i2) ea += av[i2] * w[i2 * ENC + c];
        float m = fmaxf(xv[c] + ea, 0.f);
        atomicAdd(&sagg[c * NHALF + off], m);   // ds_add_f32, stays in-CU
      }
    }
  }
  __syncthreads();

  float* pb = partial + (size_t)L * NHALF * ENC;  // dense [node'][ch] partial
  for (int n = t; n < NHALF; n += 1024) {
    float4 lo = make_float4(sagg[0 * NHALF + n], sagg[1 * NHALF + n],
                            sagg[2 * NHALF + n], sagg[3 * NHALF + n]);
    float4 hi = make_float4(sagg[4 * NHALF + n], sagg[5 * NHALF + n],
                            sagg[6 * NHALF + n], sagg[7 * NHALF + n]);
    float4* dp = (float4*)(pb + (size_t)n * ENC);
    dp[0] = lo; dp[1] = hi;
  }
}

// ---------------- Kernel 3: actor head (sums ESPLIT partials inline) ----------------
__global__ __launch_bounds__(256) void k_actor(
    const float* __restrict__ x, const float* __restrict__ partial,
    const float* __restrict__ Wa1, const float* __restrict__ ba1,
    const float* __restrict__ Wa2, const float* __restrict__ ba2,
    float* __restrict__ out) {
  __shared__ float sW1[ENC * HH], sb1[HH], sW2[HH * OUTC], sb2[OUTC];
  int t = threadIdx.x;
  if (t < ENC * HH)  sW1[t] = Wa1[t];
  if (t < HH)        sb1[t] = ba1[t];
  if (t < HH * OUTC) sW2[t] = Wa2[t];
  if (t < OUTC)      sb2[t] = ba2[t];
  __syncthreads();
  int gid = blockIdx.x * 256 + t;
  if (gid >= BB * NN) return;
  int b = gid >> 12;                       // N = 4096
  int n = gid & (NN - 1);
  int h = n >> 11, np = n & (NHALF - 1);

  const float4* xp = (const float4*)(x + (size_t)gid * ENC);
  float4 xa = xp[0], xbv = xp[1];
  float4 aa = make_float4(0.f, 0.f, 0.f, 0.f), ab2 = aa;
  const float* pb = partial + ((size_t)(b * 8 + h) * NHALF + np) * ENC;
#pragma unroll
  for (int s = 0; s < ESPLIT; ++s) {
    const float4* pp = (const float4*)(pb + (size_t)s * 2 * NHALF * ENC);
    float4 lo = pp[0], hi = pp[1];
    aa.x += lo.x; aa.y += lo.y; aa.z += lo.z; aa.w += lo.w;
    ab2.x += hi.x; ab2.y += hi.y; ab2.z += hi.z; ab2.w += hi.w;
  }
  float v[ENC] = {xa.x + aa.x, xa.y + aa.y, xa.z + aa.z, xa.w + aa.w,
                  xbv.x + ab2.x, xbv.y + ab2.y, xbv.z + ab2.z, xbv.w + ab2.w};

  float hb[HH];
#pragma unroll
  for (int j = 0; j < HH; ++j) {
    float a = sb1[j];
#pragma unroll
    for (int i = 0; i < ENC; ++i) a += v[i] * sW1[i * HH + j];
    hb[j] = fmaxf(a, 0.f);
  }
  float o[OUTC];
#pragma unroll
  for (int c = 0; c < OUTC; ++c) {
    float a = sb2[c];
#pragma unroll
    for (int j = 0; j < HH; ++j) a += hb[j] * sW2[j * OUTC + c];
    o[c] = a;
  }
  if (n > 0) {
    float* op = out + (size_t)b * ROW + (size_t)(n - 1) * OUTC;
    op[0] = o[0]; op[1] = o[1]; op[2] = o[2]; op[3] = o[3];
  }
}

// ---------------- Kernel 4: critic GEMV partials, grid = B*CSPLIT ----------------
__global__ __launch_bounds__(256) void k_critic_part(
    const float* __restrict__ obsf,
    const float* __restrict__ Wc1,
    float* __restrict__ hcrit) {
  int b = blockIdx.x / CSPLIT;
  int s = blockIdx.x % CSPLIT;
  int t = threadIdx.x;
  float acc[HH];
#pragma unroll
  for (int j = 0; j < HH; ++j) acc[j] = 0.f;

  const float* ob = obsf + (size_t)b * NI;
  int i0 = s * CCHUNK;
  for (int i = i0 + t; i < i0 + CCHUNK; i += 256) {
    float v = ob[i];
    const float4* wr = (const float4*)(Wc1 + (size_t)i * HH);
    float4 w0 = wr[0], w1 = wr[1], w2 = wr[2], w3 = wr[3];
    acc[0]  += v * w0.x; acc[1]  += v * w0.y; acc[2]  += v * w0.z; acc[3]  += v * w0.w;
    acc[4]  += v * w1.x; acc[5]  += v * w1.y; acc[6]  += v * w1.z; acc[7]  += v * w1.w;
    acc[8]  += v * w2.x; acc[9]  += v * w2.y; acc[10] += v * w2.z; acc[11] += v * w2.w;
    acc[12] += v * w3.x; acc[13] += v * w3.y; acc[14] += v * w3.z; acc[15] += v * w3.w;
  }

  __shared__ float red[4][HH];
  int wid = t >> 6, lane = t & 63;
#pragma unroll
  for (int j = 0; j < HH; ++j) {
    float a = acc[j];
#pragma unroll
    for (int off = 32; off >= 1; off >>= 1) a += __shfl_down(a, off, 64);
    if (lane == 0) red[wid][j] = a;
  }
  __syncthreads();
  if (t < HH) {
    float a = red[0][t] + red[1][t] + red[2][t] + red[3][t];
    atomicAdd(hcrit + b * HH + t, a);
  }
}

// ---------------- Kernel 5: critic finish ----------------
__global__ __launch_bounds__(64) void k_critic_fin(
    const float* __restrict__ hcrit,
    const float* __restrict__ bc1,
    const float* __restrict__ Wc2, const float* __restrict__ bc2,
    float* __restrict__ out) {
  int b = threadIdx.x;
  if (b >= BB) return;
  float val = bc2[0];
#pragma unroll
  for (int j = 0; j < HH; ++j) {
    float h = hcrit[b * HH + j] + bc1[j];
    val += fmaxf(h, 0.f) * Wc2[j];
  }
  out[(size_t)b * ROW + (ROW - 1)] = val;
}

extern "C" void kernel_launch(void* const* d_in, const int* in_sizes, int n_in,
                              void* d_out, int out_size, void* d_ws, size_t ws_size,
                              hipStream_t stream) {
  const float* agent_obs  = (const float*)d_in[0];
  const float* edge_attr  = (const float*)d_in[1];
  const float* obs_flat   = (const float*)d_in[2];
  const int*   edge_index = (const int*)d_in[3];
  const float* W_ne1 = (const float*)d_in[4];
  const float* b_ne1 = (const float*)d_in[5];
  const float* W_ne2 = (const float*)d_in[6];
  const float* b_ne2 = (const float*)d_in[7];
  const float* W_ee  = (const float*)d_in[8];
  const float* b_ee  = (const float*)d_in[9];
  const float* W_a1  = (const float*)d_in[10];
  const float* b_a1  = (const float*)d_in[11];
  const float* W_a2  = (const float*)d_in[12];
  const float* b_a2  = (const float*)d_in[13];
  const float* W_c1  = (const float*)d_in[14];
  const float* b_c1  = (const float*)d_in[15];
  const float* W_c2  = (const float*)d_in[16];
  const float* b_c2  = (const float*)d_in[17];
  float* out = (float*)d_out;

  float* x_buf   = (float*)d_ws;                              // B*N*ENC f32 = 4 MB
  float* partial = x_buf + (size_t)BB * NN * ENC;             // B*8*NHALF*ENC f32 = 16 MB
  float* hcrit   = partial + (size_t)BB * 8 * NHALF * ENC;    // B*HH f32 = 2 KB

  dim3 blk(256);
  k_node_enc<<<dim3((BB * NN) / 256), blk, 0, stream>>>(
      agent_obs, W_ne1, b_ne1, W_ne2, b_ne2, x_buf, hcrit);
  k_edge_lds<<<dim3(BB * 2 * ESPLIT), dim3(1024), 0, stream>>>(
      edge_attr, edge_index, W_ee, b_ee, x_buf, partial);
  k_actor<<<dim3((BB * NN) / 256), blk, 0, stream>>>(
      x_buf, partial, W_a1, b_a1, W_a2, b_a2, out);
  k_critic_part<<<dim3(BB * CSPLIT), blk, 0, stream>>>(
      obs_flat, W_c1, hcrit);
  k_critic_fin<<<dim3(1), dim3(64), 0, stream>>>(
      hcrit, b_c1, W_c2, b_c2, out);
}